// Round 13
// baseline (367.255 us; speedup 1.0000x reference)
//
#include <hip/hip_runtime.h>

#define HDIM 128
#define GCOUNT 64
#define CHUNK 2048

// ---- bf16 helpers (manual, RNE) ----
__device__ __forceinline__ float bfl(unsigned u) { return __uint_as_float(u << 16); }
__device__ __forceinline__ float bfh(unsigned u) { return __uint_as_float(u & 0xffff0000u); }
__device__ __forceinline__ unsigned short f2bf(float f) {
  unsigned u = __float_as_uint(f);
  unsigned r = (u + 0x7fffu + ((u >> 16) & 1u)) >> 16;
  return (unsigned short)r;
}
__device__ __forceinline__ unsigned pk2(float a, float b) {
  return (unsigned)f2bf(a) | ((unsigned)f2bf(b) << 16);
}

typedef __attribute__((ext_vector_type(8))) short short8;
typedef __attribute__((ext_vector_type(4))) float f32x4;

// biased-uint8 quant: u = round(v*rinv) + 128  (q in [-127,127] -> u in [1,255])
__device__ __forceinline__ unsigned qbu(float v, float rinv) {
  int q = (int)rintf(v * rinv) + 128;
  return (unsigned)(q & 0xff);
}

// ------- mega1: weight transpose | zero pooled/gcnt | coarse hist | prescale u8 -------

__global__ void mega1(const float* __restrict__ W0, const float* __restrict__ W1,
                      const float* __restrict__ W2,
                      unsigned short* __restrict__ h0, unsigned short* __restrict__ l0,
                      unsigned short* __restrict__ h1, unsigned short* __restrict__ l1,
                      unsigned short* __restrict__ h2, unsigned short* __restrict__ l2,
                      float* __restrict__ pooled, float* __restrict__ gcnt, int pz,
                      const int* __restrict__ dst, int E, int G, int NB1,
                      int* __restrict__ gcount,
                      const float* __restrict__ x, uint2* __restrict__ S,
                      float* __restrict__ cs_base, int n) {
  __shared__ int hist[512];
  int b = blockIdx.x, t = threadIdx.x;
  if (b < 192) {
    int w = b >> 6;
    int idx = (b & 63) * 256 + t;
    const float* W = (w == 0) ? W0 : (w == 1) ? W1 : W2;
    unsigned short* hi = (w == 0) ? h0 : (w == 1) ? h1 : h2;
    unsigned short* lo = (w == 0) ? l0 : (w == 1) ? l1 : l2;
    int k = idx >> 7, nn = idx & 127;
    float wv = W[idx];
    unsigned short h = f2bf(wv);
    float hf = __uint_as_float((unsigned)h << 16);
    unsigned short l = f2bf(wv - hf);
    hi[nn * 128 + k] = h;
    lo[nn * 128 + k] = l;
  } else if (b < 192 + pz) {
    int i = (b - 192) * 256 + t;
    if (i < GCOUNT * HDIM) pooled[i] = 0.f;
    else if (i - GCOUNT * HDIM < GCOUNT) gcnt[i - GCOUNT * HDIM] = 0.f;
  } else if (b < 192 + pz + G) {
    int blk = b - 192 - pz;
    for (int i = t; i < NB1; i += 256) hist[i] = 0;
    __syncthreads();
    int base = blk * CHUNK;
    #pragma unroll
    for (int j = 0; j < CHUNK / 256; j++) {
      int e = base + j * 256 + t;
      if (e < E) atomicAdd(&hist[dst[e] >> 8], 1);
    }
    __syncthreads();
    for (int i = t; i < NB1; i += 256) gcount[i * G + blk] = hist[i];
  } else {
    int idx = (b - 192 - pz - G) * 16 + (t >> 4);
    int l = t & 15;
    int ridx = min(idx, n - 1);
    float4 f0 = ((const float4*)x)[(size_t)ridx * 32 + l * 2];
    float4 f1 = ((const float4*)x)[(size_t)ridx * 32 + l * 2 + 1];
    float v0 = f0.x, v1 = f0.y, v2 = f0.z, v3 = f0.w;
    float v4 = f1.x, v5 = f1.y, v6 = f1.z, v7 = f1.w;
    float mx = fmaxf(fmaxf(fmaxf(fabsf(v0), fabsf(v1)), fmaxf(fabsf(v2), fabsf(v3))),
                     fmaxf(fmaxf(fabsf(v4), fabsf(v5)), fmaxf(fabsf(v6), fabsf(v7))));
    mx = fmaxf(mx, __shfl_xor(mx, 1));
    mx = fmaxf(mx, __shfl_xor(mx, 2));
    mx = fmaxf(mx, __shfl_xor(mx, 4));
    mx = fmaxf(mx, __shfl_xor(mx, 8));
    float c = mx * (1.0f / 127.0f);
    float rinv = (mx > 0.f) ? 127.0f / mx : 0.f;
    if (idx < n) {
      unsigned lo = qbu(v0, rinv) | (qbu(v1, rinv) << 8) | (qbu(v2, rinv) << 16) | (qbu(v3, rinv) << 24);
      unsigned hi = qbu(v4, rinv) | (qbu(v5, rinv) << 8) | (qbu(v6, rinv) << 16) | (qbu(v7, rinv) << 24);
      S[(size_t)idx * 16 + l] = make_uint2(lo, hi);
      if (l == 0) cs_base[idx] = c;
    }
  }
}

// ------- scanA (1024 threads): per-block exclusive scan + block totals -------

__global__ void scanA(int* __restrict__ g, int* __restrict__ bsum, int M) {
  __shared__ int sh[1024];
  int t = threadIdx.x;
  int i = blockIdx.x * 1024 + t;
  int v = (i < M) ? g[i] : 0;
  sh[t] = v;
  __syncthreads();
  for (int off = 1; off < 1024; off <<= 1) {
    int u = (t >= off) ? sh[t - off] : 0;
    __syncthreads();
    sh[t] += u;
    __syncthreads();
  }
  if (i < M) g[i] = sh[t] - v;
  if (t == 1023) bsum[blockIdx.x] = sh[1023];
}

// ------- rs_scatter (512 thr): redundant bsum scan + coarse-bucket scatter -------

__global__ void rs_scatter(const int* __restrict__ src, const int* __restrict__ dst,
                           const int* __restrict__ gA, const int* __restrict__ bsum,
                           int nbM, int E, int G, int NB1, uint2* __restrict__ sp) {
  __shared__ int bs[512];
  __shared__ int run[512];
  int blk = blockIdx.x, t = threadIdx.x;
  int v = (t < nbM) ? bsum[t] : 0;
  bs[t] = v;
  __syncthreads();
  for (int off = 1; off < 512; off <<= 1) {
    int u = (t >= off) ? bs[t - off] : 0;
    __syncthreads();
    bs[t] += u;
    __syncthreads();
  }
  for (int i = t; i < NB1; i += 512) {
    int idx = i * G + blk;
    int j = idx >> 10;
    run[i] = gA[idx] + (j ? bs[j - 1] : 0);
  }
  __syncthreads();
  int base = blk * CHUNK;
  #pragma unroll
  for (int j = 0; j < CHUNK / 512; j++) {
    int e = base + j * 512 + t;
    if (e < E) {
      int d = dst[e];
      int pos = atomicAdd(&run[d >> 8], 1);
      sp[pos] = make_uint2((unsigned)d, (unsigned)src[e]);
    }
  }
}

// ------- csr_fine (512 thr): redundant bsum scan; rowp/col/dinv/cs per bucket -------

__global__ void csr_fine(const uint2* __restrict__ sp, const int* __restrict__ gA,
                         const int* __restrict__ bsum, int nbM,
                         int E, int G, int NB1,
                         int* __restrict__ rowp, int* __restrict__ colv,
                         float* __restrict__ dinv, const float* __restrict__ cs_base,
                         float* __restrict__ cs, int n) {
  __shared__ int bs[512];
  __shared__ int hist[256];
  __shared__ int scn[256];
  __shared__ int run2[256];
  int hb = blockIdx.x, t = threadIdx.x;
  int v0 = (t < nbM) ? bsum[t] : 0;
  bs[t] = v0;
  __syncthreads();
  for (int off = 1; off < 512; off <<= 1) {
    int u = (t >= off) ? bs[t - off] : 0;
    __syncthreads();
    bs[t] += u;
    __syncthreads();
  }
  int idx0 = hb * G;
  int j0 = idx0 >> 10;
  int O = gA[idx0] + (j0 ? bs[j0 - 1] : 0);
  int Oe;
  if (hb == NB1 - 1) Oe = E;
  else {
    int idx1 = (hb + 1) * G;
    int j1 = idx1 >> 10;
    Oe = gA[idx1] + (j1 ? bs[j1 - 1] : 0);
  }
  if (t < 256) hist[t] = 0;
  __syncthreads();
  for (int e = O + t; e < Oe; e += 512) atomicAdd(&hist[sp[e].x & 255], 1);
  __syncthreads();
  int v = 0;
  if (t < 256) { v = hist[t]; scn[t] = v; }
  __syncthreads();
  for (int off = 1; off < 256; off <<= 1) {
    int u = (t < 256 && t >= off) ? scn[t - off] : 0;
    __syncthreads();
    if (t < 256) scn[t] += u;
    __syncthreads();
  }
  if (t < 256) {
    int excl = scn[t] - v;
    run2[t] = O + excl;
    int d = (hb << 8) + t;
    rowp[d] = O + excl;
    if (d < n) {
      float dv = rsqrtf((float)v + 1.0f);
      dinv[d] = dv;
      cs[d] = cs_base[d] * dv;
    }
  }
  if (hb == NB1 - 1 && t == 0) rowp[n] = E;
  __syncthreads();
  for (int e = O + t; e < Oe; e += 512) {
    uint2 p = sp[e];
    int pos = atomicAdd(&run2[p.x & 255], 1);
    colv[pos] = (int)p.y;
  }
}

// ------- aggregation (biased-u8 state; cvt_f32_ubyte dequant + scale-sum trick) -------
// out[k] = dinv * (Sum_j c_j*u_jk - 128*Sum_j c_j)

__device__ __forceinline__ void accu8(uint2 v, float c, float* a) {
  unsigned x = v.x, y = v.y;
  a[0] += c * (float)(x & 0xffu);
  a[1] += c * (float)((x >> 8) & 0xffu);
  a[2] += c * (float)((x >> 16) & 0xffu);
  a[3] += c * (float)(x >> 24);
  a[4] += c * (float)(y & 0xffu);
  a[5] += c * (float)((y >> 8) & 0xffu);
  a[6] += c * (float)((y >> 16) & 0xffu);
  a[7] += c * (float)(y >> 24);
}

__global__ void agg_i8(const uint2* __restrict__ S, const float* __restrict__ cs,
                       const float* __restrict__ dinv,
                       const int* __restrict__ rowp, const int* __restrict__ col,
                       uint4* __restrict__ OUT, int n) {
  int g = (blockIdx.x * blockDim.x + threadIdx.x) >> 4;
  int lane = threadIdx.x & 15;
  if (g >= n) return;
  float a[8] = {0.f, 0.f, 0.f, 0.f, 0.f, 0.f, 0.f, 0.f};
  float csum;
  {
    uint2 q = S[(size_t)g * 16 + lane];
    float c = cs[g];
    csum = c;
    accu8(q, c, a);
  }
  int e0 = rowp[g], e1 = rowp[g + 1];
  int e = e0;
  for (; e + 3 < e1; e += 4) {
    int s0 = col[e], s1 = col[e + 1], s2 = col[e + 2], s3 = col[e + 3];
    uint2 q0 = S[(size_t)s0 * 16 + lane];
    uint2 q1 = S[(size_t)s1 * 16 + lane];
    uint2 q2 = S[(size_t)s2 * 16 + lane];
    uint2 q3 = S[(size_t)s3 * 16 + lane];
    float c0 = cs[s0], c1 = cs[s1], c2 = cs[s2], c3 = cs[s3];
    accu8(q0, c0, a); accu8(q1, c1, a); accu8(q2, c2, a); accu8(q3, c3, a);
    csum += c0 + c1 + c2 + c3;
  }
  for (; e < e1; e++) {
    int s = col[e];
    uint2 q = S[(size_t)s * 16 + lane];
    float c = cs[s];
    accu8(q, c, a);
    csum += c;
  }
  float d = dinv[g];
  float boff = 128.f * csum;
  uint4 o;
  o.x = pk2((a[0] - boff) * d, (a[1] - boff) * d);
  o.y = pk2((a[2] - boff) * d, (a[3] - boff) * d);
  o.z = pk2((a[4] - boff) * d, (a[5] - boff) * d);
  o.w = pk2((a[6] - boff) * d, (a[7] - boff) * d);
  OUT[(size_t)g * 16 + lane] = o;
}

// ------- MFMA GEMM (LDS-staged weights) -> biased-u8 state (layers 0,1) -------

__global__ __launch_bounds__(256) void gemm_mfma_q8(
    const uint4* __restrict__ A, const uint4* __restrict__ WThi, const uint4* __restrict__ WTlo,
    const float* __restrict__ bias, const float* __restrict__ dinv,
    unsigned char* __restrict__ Sout, float* __restrict__ csout, int n) {
  __shared__ char smem[34816];
  __shared__ float Lc[64];
  uint4* Wl = (uint4*)smem;
  int t = threadIdx.x;
  int lane = t & 63, wv = t >> 6;
  int m = lane & 15, quad = lane >> 4;
  int block0 = blockIdx.x * 64;
  int arow = block0 + wv * 16 + m;
  uint4 av[4];
  #pragma unroll
  for (int kb = 0; kb < 4; kb++)
    av[kb] = (arow < n) ? A[(size_t)arow * 16 + kb * 4 + quad] : make_uint4(0, 0, 0, 0);
  f32x4 acc[8];
  #pragma unroll
  for (int i = 0; i < 8; i++) acc[i] = (f32x4){0.f, 0.f, 0.f, 0.f};

  #pragma unroll
  for (int i = 0; i < 8; i++) {
    int idx = t + i * 256;
    Wl[(idx >> 4) * 17 + (idx & 15)] = WThi[idx];
  }
  __syncthreads();
  #pragma unroll
  for (int kb = 0; kb < 4; kb++) {
    short8 af = __builtin_bit_cast(short8, av[kb]);
    #pragma unroll
    for (int nt = 0; nt < 8; nt++) {
      uint4 bh = Wl[(nt * 16 + m) * 17 + kb * 4 + quad];
      acc[nt] = __builtin_amdgcn_mfma_f32_16x16x32_bf16(af, __builtin_bit_cast(short8, bh), acc[nt], 0, 0, 0);
    }
  }
  __syncthreads();
  #pragma unroll
  for (int i = 0; i < 8; i++) {
    int idx = t + i * 256;
    Wl[(idx >> 4) * 17 + (idx & 15)] = WTlo[idx];
  }
  __syncthreads();
  #pragma unroll
  for (int kb = 0; kb < 4; kb++) {
    short8 af = __builtin_bit_cast(short8, av[kb]);
    #pragma unroll
    for (int nt = 0; nt < 8; nt++) {
      uint4 bl = Wl[(nt * 16 + m) * 17 + kb * 4 + quad];
      acc[nt] = __builtin_amdgcn_mfma_f32_16x16x32_bf16(af, __builtin_bit_cast(short8, bl), acc[nt], 0, 0, 0);
    }
  }
  __syncthreads();

  #pragma unroll
  for (int r = 0; r < 4; r++) {
    int lrow = wv * 16 + quad * 4 + r;
    int grow = block0 + lrow;
    float sc = (grow < n) ? dinv[grow] : 0.f;
    float v[8];
    float mx = 0.f;
    #pragma unroll
    for (int nt = 0; nt < 8; nt++) {
      v[nt] = fmaxf(acc[nt][r] + bias[nt * 16 + m], 0.f) * sc;
      mx = fmaxf(mx, v[nt]);
    }
    mx = fmaxf(mx, __shfl_xor(mx, 1));
    mx = fmaxf(mx, __shfl_xor(mx, 2));
    mx = fmaxf(mx, __shfl_xor(mx, 4));
    mx = fmaxf(mx, __shfl_xor(mx, 8));
    float c = mx * (1.0f / 127.0f);
    float rinv = (mx > 0.f) ? 127.0f / mx : 0.f;
    #pragma unroll
    for (int nt = 0; nt < 8; nt++) {
      smem[lrow * 144 + nt * 16 + m] = (char)(unsigned char)(((int)rintf(v[nt] * rinv) + 128) & 0xff);
    }
    if (m == 0) Lc[lrow] = c;
  }
  __syncthreads();
  for (int i = t; i < 512; i += 256) {
    int lrow = i >> 3, seg = i & 7;
    int grow = block0 + lrow;
    if (grow < n)
      ((uint4*)Sout)[(size_t)grow * 8 + seg] = *(const uint4*)&smem[lrow * 144 + seg * 16];
  }
  if (t < 64 && block0 + t < n) csout[block0 + t] = Lc[t];
}

// ------- MFMA GEMM (LDS-staged weights) -> bf16 out (final layer) -------

__global__ __launch_bounds__(256) void gemm_mfma(
    const uint4* __restrict__ A, const uint4* __restrict__ WThi, const uint4* __restrict__ WTlo,
    const float* __restrict__ bias, unsigned short* __restrict__ Y, int n) {
  __shared__ char smem[34816];
  uint4* Wl = (uint4*)smem;
  int t = threadIdx.x;
  int lane = t & 63, wv = t >> 6;
  int m = lane & 15, quad = lane >> 4;
  int block0 = blockIdx.x * 64;
  int arow = block0 + wv * 16 + m;
  uint4 av[4];
  #pragma unroll
  for (int kb = 0; kb < 4; kb++)
    av[kb] = (arow < n) ? A[(size_t)arow * 16 + kb * 4 + quad] : make_uint4(0, 0, 0, 0);
  f32x4 acc[8];
  #pragma unroll
  for (int i = 0; i < 8; i++) acc[i] = (f32x4){0.f, 0.f, 0.f, 0.f};

  #pragma unroll
  for (int i = 0; i < 8; i++) {
    int idx = t + i * 256;
    Wl[(idx >> 4) * 17 + (idx & 15)] = WThi[idx];
  }
  __syncthreads();
  #pragma unroll
  for (int kb = 0; kb < 4; kb++) {
    short8 af = __builtin_bit_cast(short8, av[kb]);
    #pragma unroll
    for (int nt = 0; nt < 8; nt++) {
      uint4 bh = Wl[(nt * 16 + m) * 17 + kb * 4 + quad];
      acc[nt] = __builtin_amdgcn_mfma_f32_16x16x32_bf16(af, __builtin_bit_cast(short8, bh), acc[nt], 0, 0, 0);
    }
  }
  __syncthreads();
  #pragma unroll
  for (int i = 0; i < 8; i++) {
    int idx = t + i * 256;
    Wl[(idx >> 4) * 17 + (idx & 15)] = WTlo[idx];
  }
  __syncthreads();
  #pragma unroll
  for (int kb = 0; kb < 4; kb++) {
    short8 af = __builtin_bit_cast(short8, av[kb]);
    #pragma unroll
    for (int nt = 0; nt < 8; nt++) {
      uint4 bl = Wl[(nt * 16 + m) * 17 + kb * 4 + quad];
      acc[nt] = __builtin_amdgcn_mfma_f32_16x16x32_bf16(af, __builtin_bit_cast(short8, bl), acc[nt], 0, 0, 0);
    }
  }
  __syncthreads();

  unsigned short* Ls = (unsigned short*)smem;
  #pragma unroll
  for (int r = 0; r < 4; r++) {
    int lrow = wv * 16 + quad * 4 + r;
    #pragma unroll
    for (int nt = 0; nt < 8; nt++) {
      float v = fmaxf(acc[nt][r] + bias[nt * 16 + m], 0.f);
      Ls[lrow * 136 + nt * 16 + m] = f2bf(v);
    }
  }
  __syncthreads();
  for (int i = t; i < 1024; i += 256) {
    int lrow = i >> 4, seg = i & 15;
    int grow = block0 + lrow;
    if (grow < n)
      ((uint4*)Y)[(size_t)grow * 16 + seg] = *(const uint4*)&smem[lrow * 272 + seg * 16];
  }
}

// ------- mean pool (batch sorted, bf16 input; parallel) -------

__global__ void pool_kernel(const unsigned short* __restrict__ X, const int* __restrict__ batch,
                            float* __restrict__ pooled, float* __restrict__ gcnt, int n) {
  int t = threadIdx.x;
  int r0 = blockIdx.x * 64;
  if (r0 >= n) return;
  int r1 = min(r0 + 64, n);
  int g = batch[r0];
  float acc = 0.f, cl = 0.f;
  for (int r = r0; r < r1; r++) {
    int gr = batch[r];
    if (gr != g) {
      atomicAdd(&pooled[g * HDIM + t], acc);
      if (t == 0) atomicAdd(&gcnt[g], cl);
      acc = 0.f; cl = 0.f; g = gr;
    }
    acc += __uint_as_float((unsigned)X[(size_t)r * HDIM + t] << 16);
    cl += 1.f;
  }
  atomicAdd(&pooled[g * HDIM + t], acc);
  if (t == 0) atomicAdd(&gcnt[g], cl);
}

// ------- classifier head -------

__global__ void cls_kernel(const float* __restrict__ pooled, const float* __restrict__ gcnt,
                           const float* __restrict__ Wc1, const float* __restrict__ bc1,
                           const float* __restrict__ Wc2, const float* __restrict__ bc2,
                           float* __restrict__ out) {
  __shared__ float p[HDIM];
  __shared__ float r0s[HDIM], r1s[HDIM];
  int g = blockIdx.x, t = threadIdx.x;
  float c = fmaxf(gcnt[g], 1.0f);
  p[t] = pooled[g * HDIM + t] / c;
  __syncthreads();
  float acc = bc1[t];
  for (int k = 0; k < HDIM; k++) {
    acc += p[k] * (Wc1[k * HDIM + t] + Wc1[(HDIM + k) * HDIM + t]);
  }
  float h = fmaxf(acc, 0.f);
  r0s[t] = h * Wc2[t * 2 + 0];
  r1s[t] = h * Wc2[t * 2 + 1];
  __syncthreads();
  for (int s2 = 64; s2 > 0; s2 >>= 1) {
    if (t < s2) { r0s[t] += r0s[t + s2]; r1s[t] += r1s[t + s2]; }
    __syncthreads();
  }
  if (t == 0) {
    out[g * 2 + 0] = r0s[0] + bc2[0];
    out[g * 2 + 1] = r1s[0] + bc2[1];
  }
}

// ------- launch -------

extern "C" void kernel_launch(void* const* d_in, const int* in_sizes, int n_in,
                              void* d_out, int out_size, void* d_ws, size_t ws_size,
                              hipStream_t stream) {
  const float* x   = (const float*)d_in[0];
  const int*   ei  = (const int*)d_in[1];
  const int*   bat = (const int*)d_in[2];
  const float* W0  = (const float*)d_in[3];
  const float* b0  = (const float*)d_in[4];
  const float* W1  = (const float*)d_in[5];
  const float* b1  = (const float*)d_in[6];
  const float* W2  = (const float*)d_in[7];
  const float* b2  = (const float*)d_in[8];
  const float* Wc1 = (const float*)d_in[9];
  const float* bc1 = (const float*)d_in[10];
  const float* Wc2 = (const float*)d_in[11];
  const float* bc2 = (const float*)d_in[12];
  float* out = (float*)d_out;

  int N = in_sizes[0] / HDIM;
  int E = in_sizes[1] / 2;
  const int* src = ei;
  const int* dst = ei + E;

  int NB1 = (N + 255) >> 8;
  int G = (E + CHUNK - 1) / CHUNK;
  int M = NB1 * G;

  char* ws = (char*)d_ws;
  size_t off = 0;
  auto alloc = [&](size_t bytes) -> void* {
    void* p = (void*)(ws + off);
    off += (bytes + 511) & ~(size_t)511;
    return p;
  };
  unsigned char* Sa = (unsigned char*)alloc((size_t)N * HDIM * 2);
  unsigned char* Sb = Sa + (size_t)N * HDIM;
  unsigned short* H = (unsigned short*)Sa;
  unsigned short* Abuf = (unsigned short*)alloc((size_t)N * HDIM * 2);
  float* csa  = (float*)alloc((size_t)N * 4);
  float* csb  = (float*)alloc((size_t)N * 4);
  float* cs_base = (float*)alloc((size_t)N * 4);
  float* dinv = (float*)alloc((size_t)N * 4);
  int*   rowp = (int*)alloc((size_t)(NB1 * 256 + 2) * 4);
  int*   colv = (int*)alloc((size_t)E * 4);
  uint2* sp   = (uint2*)alloc((size_t)E * 8);
  float* pooled = (float*)alloc((size_t)GCOUNT * HDIM * 4);
  float* gcnt   = (float*)alloc((size_t)GCOUNT * 4);
  unsigned short* wt_hi[3], *wt_lo[3];
  for (int i = 0; i < 3; i++) {
    wt_hi[i] = (unsigned short*)alloc(HDIM * HDIM * 2);
    wt_lo[i] = (unsigned short*)alloc(HDIM * HDIM * 2);
  }
  int* gcount = (int*)alloc((size_t)(M + 2) * 4);
  int nbM = (M + 1023) / 1024;
  int* bsum = (int*)alloc((size_t)(nbM + 2) * 4);

  // 1. mega1
  int pz = (GCOUNT * HDIM + GCOUNT + 255) / 256;
  int psb = (N + 15) / 16;
  mega1<<<192 + pz + G + psb, 256, 0, stream>>>(W0, W1, W2,
      wt_hi[0], wt_lo[0], wt_hi[1], wt_lo[1], wt_hi[2], wt_lo[2],
      pooled, gcnt, pz, dst, E, G, NB1, gcount,
      x, (uint2*)Sa, cs_base, N);

  // 2. scanA only (block offsets folded into consumers)
  scanA<<<nbM, 1024, 0, stream>>>(gcount, bsum, M);

  // 3-4. scatter + fine CSR (each redundantly scans bsum in LDS)
  rs_scatter<<<G, 512, 0, stream>>>(src, dst, gcount, bsum, nbM, E, G, NB1, sp);
  csr_fine<<<NB1, 512, 0, stream>>>(sp, gcount, bsum, nbM, E, G, NB1, rowp, colv,
      dinv, cs_base, csa, N);

  // 5-10. agg + gemm ping-pong
  int aggBlocks = (N + 15) / 16;
  int gemmBlocks = (N + 63) / 64;

  agg_i8<<<aggBlocks, 256, 0, stream>>>((const uint2*)Sa, csa, dinv, rowp, colv, (uint4*)Abuf, N);
  gemm_mfma_q8<<<gemmBlocks, 256, 0, stream>>>((const uint4*)Abuf, (const uint4*)wt_hi[0],
      (const uint4*)wt_lo[0], b0, dinv, Sb, csb, N);

  agg_i8<<<aggBlocks, 256, 0, stream>>>((const uint2*)Sb, csb, dinv, rowp, colv, (uint4*)Abuf, N);
  gemm_mfma_q8<<<gemmBlocks, 256, 0, stream>>>((const uint4*)Abuf, (const uint4*)wt_hi[1],
      (const uint4*)wt_lo[1], b1, dinv, Sa, csa, N);

  agg_i8<<<aggBlocks, 256, 0, stream>>>((const uint2*)Sa, csa, dinv, rowp, colv, (uint4*)Abuf, N);
  gemm_mfma<<<gemmBlocks, 256, 0, stream>>>((const uint4*)Abuf, (const uint4*)wt_hi[2],
      (const uint4*)wt_lo[2], b2, H, N);

  // 11-12. pool + classifier
  pool_kernel<<<(N + 63) / 64, 128, 0, stream>>>(H, bat, pooled, gcnt, N);
  cls_kernel<<<GCOUNT, HDIM, 0, stream>>>(pooled, gcnt, Wc1, bc1, Wc2, bc2, out);
}